// Round 7
// baseline (252.483 us; speedup 1.0000x reference)
//
#include <hip/hip_runtime.h>
#include <hip/hip_bf16.h>
#include <stdint.h>

// Problem constants (fixed by the reference)
#define B_SZ 8192
#define D_SZ 256
#define R_SZ 8
#define N_SZ 1024
#define C_SZ (B_SZ / R_SZ)          // 1024
#define CN   (C_SZ * N_SZ)          // 1048576
#define L_SZ (B_SZ + 2 * R_SZ * CN) // 16785408 (logits length)
#define BD   (B_SZ * D_SZ)          // 2097152 elems per ws array

typedef short bf16x8 __attribute__((ext_vector_type(8)));
typedef float f32x4  __attribute__((ext_vector_type(4)));

static __device__ __forceinline__ unsigned short f2bf(float f) {
  unsigned u = __float_as_uint(f);
  u += 0x7FFFu + ((u >> 16) & 1u);   // RNE
  return (unsigned short)(u >> 16);
}
static __device__ __forceinline__ float bf2f(unsigned short h) {
  return __uint_as_float(((unsigned)h) << 16);
}
static __device__ __forceinline__ float sigmoidf_(float x) {
  return 1.0f / (1.0f + __expf(-x));
}
static __device__ __forceinline__ void gload16(const void* g, void* l) {
  __builtin_amdgcn_global_load_lds(
      (const __attribute__((address_space(1))) void*)g,
      (__attribute__((address_space(3))) void*)l, 16, 0, 0);
}

// ws layout (bytes):
//   0    : lhs_hi_s (4MB)   sorted by relation: row p = r*1024 + c
//   4MB  : lhs_lo_s
//   8MB  : rhs_hi_s
//   12MB : rhs_lo_s
//   16MB : inv (32KB int)   inv[order[j]] = j

// ---------------------------------------------------------------------------
__global__ void inv_kernel(const int* __restrict__ order, int* __restrict__ inv) {
  int j = blockIdx.x * 256 + threadIdx.x;
  inv[order[j]] = j;
}

// ---------------------------------------------------------------------------
// Phase 1: F-reduce emb -> lhs/rhs, split bf16 hi+lo, SCATTER to sorted rows.
// ---------------------------------------------------------------------------
__global__ __launch_bounds__(256) void prep_kernel(
    const float* __restrict__ emb, const float* __restrict__ trans,
    const int* __restrict__ rels, const int* __restrict__ inv,
    float* __restrict__ out, unsigned short* __restrict__ sortArr) {
  unsigned short* lhs_hi = sortArr;
  unsigned short* lhs_lo = sortArr + (size_t)BD;
  unsigned short* rhs_hi = sortArr + (size_t)2 * BD;
  unsigned short* rhs_lo = sortArr + (size_t)3 * BD;

  int wave = threadIdx.x >> 6;
  int lane = threadIdx.x & 63;
  int i = blockIdx.x * 4 + wave;            // 0..B-1

  const float4* emb4 = (const float4*)emb;  // emb row j = 128 float4 (F*D=512 f32)
  size_t bl = (size_t)(2 * i) * 128;
  size_t br = (size_t)(2 * i + 1) * 128;
  float4 a0 = emb4[bl + lane];
  float4 a1 = emb4[bl + 64 + lane];
  float4 b0 = emb4[br + lane];
  float4 b1 = emb4[br + 64 + lane];
  float lh[4] = {a0.x + a1.x, a0.y + a1.y, a0.z + a1.z, a0.w + a1.w};
  float rh[4] = {b0.x + b1.x, b0.y + b1.y, b0.z + b1.z, b0.w + b1.w};

  int rel = rels[i];
  float4 tv = ((const float4*)trans)[rel * 64 + lane];
  float tt[4] = {tv.x, tv.y, tv.z, tv.w};

  float p = 0.f;
#pragma unroll
  for (int j = 0; j < 4; ++j) p += lh[j] * (rh[j] + tt[j]);
#pragma unroll
  for (int off = 32; off; off >>= 1) p += __shfl_xor(p, off, 64);
  if (lane == 0) {
    out[i] = p;
    out[(size_t)L_SZ + i] = sigmoidf_(p);
  }

  int sp = inv[i];  // sorted row
  unsigned short h[4], l[4];
#pragma unroll
  for (int j = 0; j < 4; ++j) {
    h[j] = f2bf(lh[j]);
    l[j] = f2bf(lh[j] - bf2f(h[j]));
  }
  *(ushort4*)(lhs_hi + (size_t)sp * 256 + lane * 4) = make_ushort4(h[0], h[1], h[2], h[3]);
  *(ushort4*)(lhs_lo + (size_t)sp * 256 + lane * 4) = make_ushort4(l[0], l[1], l[2], l[3]);
#pragma unroll
  for (int j = 0; j < 4; ++j) {
    h[j] = f2bf(rh[j]);
    l[j] = f2bf(rh[j] - bf2f(h[j]));
  }
  *(ushort4*)(rhs_hi + (size_t)sp * 256 + lane * 4) = make_ushort4(h[0], h[1], h[2], h[3]);
  *(ushort4*)(rhs_lo + (size_t)sp * 256 + lane * 4) = make_ushort4(l[0], l[1], l[2], l[3]);
}

// ---------------------------------------------------------------------------
// Phase 2: ONE double-gathered GEMM per (r, tA, tB) serves BOTH output sides.
//   T[i',j'] = samp_rhs[tA*128+i'] . samp_lhs[tB*128+j']   (K=256, split-bf16)
//   negs_lhs[sR(i'), tB*128+j'] = T[i',j']   (direct from acc)
//   negs_rhs[sL(j'), tA*128+i'] = T[i',j']   (via swizzled LDS transpose)
// 512 blocks (2/CU, one generation), 4 waves 2x2, BK=32, dbuf 2x32KB LDS.
// T3-minimum schedule: STAGE(next) before compute; ONE __syncthreads per tile.
// XOR swizzles: staging chunk ^ ((row>>1)&3) (both sides); transpose chunk-of-4
// ^ (i'&31) -> <=2-way everywhere. XCD swizzle: relation r == XCD.
// ---------------------------------------------------------------------------
__global__ __launch_bounds__(256, 2) void negs_kernel(
    const unsigned short* __restrict__ ws, const int* __restrict__ inv,
    const int* __restrict__ negL, const int* __restrict__ negR,
    float* __restrict__ out) {
  __shared__ char lds[2][32768];  // stage dbuf; reused post-loop as float tr[128][128]
  __shared__ int sR[128], sL[128];

  const char* base0 = (const char*)ws;

  int hw = blockIdx.x;
  int bid = (hw & 7) * 64 + (hw >> 3);   // bijective: 512 = 8 XCD x 64; r == XCD
  int tB = bid & 7;
  int tA = (bid >> 3) & 7;
  int r  = bid >> 6;

  int t = threadIdx.x;
  int wave = t >> 6, lane = t & 63;
  int wrow = wave >> 1, wcol = wave & 1;
  int lx = lane & 15;

  // Permutation tables for the epilogue (block-local sorted positions).
  if (t < 128) sR[t] = inv[negR[r * N_SZ + tA * 128 + t]] - r * C_SZ;
  else sL[t - 128] = inv[negL[r * N_SZ + tB * 128 + (t - 128)]] - r * C_SZ;

  // Staging: wave w owns array w (0=Ah 1=Al 2=Bh 3=Bl; A=samp_rhs, B=samp_lhs).
  // Per tile: 8 gload16/lane; load 'it' covers rows it*16 + (lane>>2), chunk
  // lane&3; source chunk inverse-swizzled: (lane&3) ^ ((lane>>3)&3).
  unsigned srcswz = (unsigned)(((lane & 3) ^ ((lane >> 3) & 3)) << 4);
  const int* idxp = (wave < 2) ? negR : negL;
  int tbase = r * N_SZ + ((wave < 2) ? tA : tB) * 128;
  const char* srcp = base0 + ((wave < 2) ? (size_t)8 * 1024 * 1024 : 0) +
                     ((wave & 1) ? (size_t)4 * 1024 * 1024 : 0);
  unsigned goff[8];
#pragma unroll
  for (int it = 0; it < 8; ++it)
    goff[it] = (unsigned)inv[idxp[tbase + it * 16 + (lane >> 2)]] * 512u + srcswz;
  char* myLds0 = &lds[0][0] + wave * 8192;
  char* myLds1 = &lds[1][0] + wave * 8192;

  f32x4 acc[4][4] = {};
  int q = lane >> 4;  // logical 16B chunk 0..3 within 64B LDS row

  // Prologue: stage tile 0 into buf 0.
#pragma unroll
  for (int it = 0; it < 8; ++it)
    gload16(srcp + goff[it], myLds0 + it * 1024);
  __syncthreads();

#pragma unroll 1
  for (int kt = 0; kt < 8; ++kt) {
    // Stage next tile into the other buffer (covered by this tile's compute).
    if (kt < 7) {
      char* nl = (kt & 1) ? myLds0 : myLds1;
      unsigned kb = (unsigned)(kt + 1) * 64u;
#pragma unroll
      for (int it = 0; it < 8; ++it)
        gload16(srcp + goff[it] + kb, nl + it * 1024);
    }
    const char* L = &lds[kt & 1][0];
    bf16x8 ah[4], al_[4], bh[4], bl_[4];
#pragma unroll
    for (int mi = 0; mi < 4; ++mi) {
      int row = wrow * 64 + mi * 16 + lx;
      int off = row * 64 + ((q ^ ((row >> 1) & 3)) << 4);
      ah[mi]  = *(const bf16x8*)(L + off);
      al_[mi] = *(const bf16x8*)(L + 8192 + off);
    }
#pragma unroll
    for (int ni = 0; ni < 4; ++ni) {
      int row = wcol * 64 + ni * 16 + lx;
      int off = row * 64 + ((q ^ ((row >> 1) & 3)) << 4);
      bh[ni]  = *(const bf16x8*)(L + 16384 + off);
      bl_[ni] = *(const bf16x8*)(L + 24576 + off);
    }
#pragma unroll
    for (int mi = 0; mi < 4; ++mi)
#pragma unroll
      for (int ni = 0; ni < 4; ++ni) {
        acc[mi][ni] = __builtin_amdgcn_mfma_f32_16x16x32_bf16(ah[mi],  bh[ni],  acc[mi][ni], 0, 0, 0);
        acc[mi][ni] = __builtin_amdgcn_mfma_f32_16x16x32_bf16(al_[mi], bh[ni],  acc[mi][ni], 0, 0, 0);
        acc[mi][ni] = __builtin_amdgcn_mfma_f32_16x16x32_bf16(ah[mi],  bl_[ni], acc[mi][ni], 0, 0, 0);
      }
    __syncthreads();   // vmcnt(0)+lgkm(0)+barrier: next buffer ready, this one free
  }

  // Epilogue. C/D layout: col j' = lane&15 (+16*ni+64*wcol), row i' = (lane>>4)*4+jj (+16*mi+64*wrow).
  size_t obaseL = (size_t)B_SZ + (size_t)r * 2 * CN;        // negs_lhs part
  size_t obaseR = obaseL + CN;                               // negs_rhs part
  float* tr = (float*)&lds[0][0];                            // 64KB reuse (post-loop barrier held)

#pragma unroll
  for (int mi = 0; mi < 4; ++mi)
#pragma unroll
    for (int ni = 0; ni < 4; ++ni)
#pragma unroll
      for (int jj = 0; jj < 4; ++jj) {
        int ip = wrow * 64 + mi * 16 + ((lane >> 4) << 2) + jj;
        int jp = wcol * 64 + ni * 16 + lx;
        float v = acc[mi][ni][jj];
        // lhs side: row sR(ip), col tB*128 + jp  (64B coalesced segments)
        size_t idx = obaseL + (size_t)sR[ip] * 1024 + tB * 128 + jp;
        __builtin_nontemporal_store(v, &out[idx]);
        __builtin_nontemporal_store(sigmoidf_(v), &out[(size_t)L_SZ + idx]);
        // transpose store for rhs side (chunk-of-4 XOR swizzle)
        tr[ip * 128 + (((jp >> 2) ^ (ip & 31)) << 2) + (jp & 3)] = v;
      }
  __syncthreads();

  // rhs side: thread -> (j' = t>>1, i' half = (t&1)*64); rows sL(j'), cols tA*128+i'.
  {
    int jp = t >> 1;
    int ih = (t & 1) * 64;
    size_t rbase = obaseR + (size_t)sL[jp] * 1024 + tA * 128 + ih;
#pragma unroll 4
    for (int k0 = 0; k0 < 64; k0 += 4) {
      f32x4 v4, s4;
#pragma unroll
      for (int u = 0; u < 4; ++u) {
        int ip = ih + k0 + u;
        float v = tr[ip * 128 + (((jp >> 2) ^ (ip & 31)) << 2) + (jp & 3)];
        v4[u] = v;
        s4[u] = sigmoidf_(v);
      }
      __builtin_nontemporal_store(v4, (f32x4*)(out + rbase + k0));
      __builtin_nontemporal_store(s4, (f32x4*)(out + (size_t)L_SZ + rbase + k0));
    }
  }
}

// ---------------------------------------------------------------------------
extern "C" void kernel_launch(void* const* d_in, const int* in_sizes, int n_in,
                              void* d_out, int out_size, void* d_ws, size_t ws_size,
                              hipStream_t stream) {
  const float* emb   = (const float*)d_in[0];
  const float* trans = (const float*)d_in[1];
  const int*   rels  = (const int*)d_in[2];
  const int*   order = (const int*)d_in[3];
  const int*   negL  = (const int*)d_in[4];
  const int*   negR  = (const int*)d_in[5];
  float* out = (float*)d_out;

  unsigned short* sortArr = (unsigned short*)d_ws;
  int* inv = (int*)((char*)d_ws + (size_t)16 * 1024 * 1024);

  inv_kernel<<<32, 256, 0, stream>>>(order, inv);
  prep_kernel<<<B_SZ / 4, 256, 0, stream>>>(emb, trans, rels, inv, out, sortArr);
  negs_kernel<<<512, 256, 0, stream>>>(sortArr, inv, negL, negR, out);
}

// Round 8
// 76.415 us; speedup vs baseline: 3.3041x; 3.3041x over previous
//
#include <hip/hip_runtime.h>
#include <hip/hip_bf16.h>
#include <stdint.h>

// Problem constants (fixed by the reference)
#define B_SZ 8192
#define D_SZ 256
#define R_SZ 8
#define N_SZ 1024
#define C_SZ (B_SZ / R_SZ)          // 1024
#define CN   (C_SZ * N_SZ)          // 1048576
#define L_SZ (B_SZ + 2 * R_SZ * CN) // 16785408 (logits length)
#define BD   (B_SZ * D_SZ)          // 2097152 elems per ws array

typedef short bf16x8 __attribute__((ext_vector_type(8)));
typedef float f32x4  __attribute__((ext_vector_type(4)));

static __device__ __forceinline__ unsigned short f2bf(float f) {
  unsigned u = __float_as_uint(f);
  u += 0x7FFFu + ((u >> 16) & 1u);   // RNE
  return (unsigned short)(u >> 16);
}
static __device__ __forceinline__ float bf2f(unsigned short h) {
  return __uint_as_float(((unsigned)h) << 16);
}
static __device__ __forceinline__ float sigmoidf_(float x) {
  return 1.0f / (1.0f + __expf(-x));
}
static __device__ __forceinline__ void gload16(const void* g, void* l) {
  __builtin_amdgcn_global_load_lds(
      (const __attribute__((address_space(1))) void*)g,
      (__attribute__((address_space(3))) void*)l, 16, 0, 0);
}

// ws layout (bytes):
//   0    : lhs_hi_s (4MB)   sorted by relation: row p = r*1024 + c
//   4MB  : lhs_lo_s
//   8MB  : rhs_hi_s
//   12MB : rhs_lo_s
//   16MB : inv (32KB int)   inv[order[j]] = j

// ---------------------------------------------------------------------------
__global__ void inv_kernel(const int* __restrict__ order, int* __restrict__ inv) {
  int j = blockIdx.x * 256 + threadIdx.x;
  inv[order[j]] = j;
}

// ---------------------------------------------------------------------------
// Phase 1: F-reduce emb -> lhs/rhs, split bf16 hi+lo, SCATTER to sorted rows.
// ---------------------------------------------------------------------------
__global__ __launch_bounds__(256) void prep_kernel(
    const float* __restrict__ emb, const float* __restrict__ trans,
    const int* __restrict__ rels, const int* __restrict__ inv,
    float* __restrict__ out, unsigned short* __restrict__ sortArr) {
  unsigned short* lhs_hi = sortArr;
  unsigned short* lhs_lo = sortArr + (size_t)BD;
  unsigned short* rhs_hi = sortArr + (size_t)2 * BD;
  unsigned short* rhs_lo = sortArr + (size_t)3 * BD;

  int wave = threadIdx.x >> 6;
  int lane = threadIdx.x & 63;
  int i = blockIdx.x * 4 + wave;            // 0..B-1

  const float4* emb4 = (const float4*)emb;  // emb row j = 128 float4 (F*D=512 f32)
  size_t bl = (size_t)(2 * i) * 128;
  size_t br = (size_t)(2 * i + 1) * 128;
  float4 a0 = emb4[bl + lane];
  float4 a1 = emb4[bl + 64 + lane];
  float4 b0 = emb4[br + lane];
  float4 b1 = emb4[br + 64 + lane];
  float lh[4] = {a0.x + a1.x, a0.y + a1.y, a0.z + a1.z, a0.w + a1.w};
  float rh[4] = {b0.x + b1.x, b0.y + b1.y, b0.z + b1.z, b0.w + b1.w};

  int rel = rels[i];
  float4 tv = ((const float4*)trans)[rel * 64 + lane];
  float tt[4] = {tv.x, tv.y, tv.z, tv.w};

  float p = 0.f;
#pragma unroll
  for (int j = 0; j < 4; ++j) p += lh[j] * (rh[j] + tt[j]);
#pragma unroll
  for (int off = 32; off; off >>= 1) p += __shfl_xor(p, off, 64);
  if (lane == 0) {
    out[i] = p;
    out[(size_t)L_SZ + i] = sigmoidf_(p);
  }

  int sp = inv[i];  // sorted row
  unsigned short h[4], l[4];
#pragma unroll
  for (int j = 0; j < 4; ++j) {
    h[j] = f2bf(lh[j]);
    l[j] = f2bf(lh[j] - bf2f(h[j]));
  }
  *(ushort4*)(lhs_hi + (size_t)sp * 256 + lane * 4) = make_ushort4(h[0], h[1], h[2], h[3]);
  *(ushort4*)(lhs_lo + (size_t)sp * 256 + lane * 4) = make_ushort4(l[0], l[1], l[2], l[3]);
#pragma unroll
  for (int j = 0; j < 4; ++j) {
    h[j] = f2bf(rh[j]);
    l[j] = f2bf(rh[j] - bf2f(h[j]));
  }
  *(ushort4*)(rhs_hi + (size_t)sp * 256 + lane * 4) = make_ushort4(h[0], h[1], h[2], h[3]);
  *(ushort4*)(rhs_lo + (size_t)sp * 256 + lane * 4) = make_ushort4(l[0], l[1], l[2], l[3]);
}

// ---------------------------------------------------------------------------
// Phase 2: negatives GEMM, 256x256 tile, 8 waves (2x4), BK=64, K=768 virtual
// (segments: 0-3 Ah*Bh, 4-7 Al*Bh, 8-11 Ah*Bl), dbuf 2x64KB LDS, grid 256
// (1/CU, r == XCD). Counted-vmcnt depth-2 pipeline (T3+T4):
//   top: vmcnt(8) [step t landed, t+1 in flight]; s_barrier;
//   4 sub-phases {ds_read frags || 16 MFMA, setprio-wrapped};
//   s_barrier; STAGE(t+2 -> buf[t&1]).
// XOR chunk swizzle (chunk ^ row&7) on source + ds_read -> conflict-free.
// A rows contiguous (sorted); B rows gathered via inv[negp[...]] (precomputed).
// Epilogue: contiguous-row logits+sigmoid stores (proven pattern).
// ---------------------------------------------------------------------------
__global__ __launch_bounds__(512, 2) void negs_kernel(
    const unsigned short* __restrict__ ws, const int* __restrict__ inv,
    const int* __restrict__ negL, const int* __restrict__ negR,
    float* __restrict__ out) {
  __shared__ char lds[2][65536];  // per buf: A[256][64]bf16 @0, B[256][64] @32768

  const char* base0 = (const char*)ws;

  int hw = blockIdx.x;
  int bid = (hw & 7) * 32 + (hw >> 3);   // bijective: 256 = 8 XCD x 32; r == XCD
  int r = bid >> 5;
  int rem = bid & 31;
  int side  = rem >> 4;
  int ctile = (rem >> 2) & 3;
  int ntile = rem & 3;

  int t = threadIdx.x;
  int wave = t >> 6, lane = t & 63;
  int wrow = wave >> 2, wcol = wave & 3;   // 2 x 4 wave grid
  int lx = lane & 15;

  // side 0: A = s_rhs, B = samp_lhs ; side 1: A = s_lhs, B = samp_rhs
  const char* aHi = base0 + (side ? 0 : ((size_t)8 << 20));
  const char* aLo = aHi + ((size_t)4 << 20);
  const char* bHi = base0 + (side ? ((size_t)8 << 20) : 0);
  const char* bLo = bHi + ((size_t)4 << 20);
  const int* negp = side ? negR : negL;

  // Staging map: thread t covers rows {i*64 + (t>>3)} chunk (t&7), i=0..3,
  // for both A and B (8 gload16/step). Source chunk inverse-swizzled by row&7.
  unsigned srcswz = ((unsigned)((t & 7) ^ ((t >> 3) & 7))) << 4;
  unsigned abase = (unsigned)(r * C_SZ + ctile * 256 + (t >> 3)) * 512u + srcswz;
  unsigned boff[4];
  {
    int bidx = r * N_SZ + ntile * 256 + (t >> 3);
#pragma unroll
    for (int i = 0; i < 4; ++i)
      boff[i] = (unsigned)inv[negp[bidx + i * 64]] * 512u + srcswz;
  }

  auto STAGE = [&](int step, int buf) {
    int seg = step >> 2;
    unsigned kb = (unsigned)(step & 3) * 128u;
    const char* pa = (seg == 1) ? aLo : aHi;
    const char* pb = (seg == 2) ? bLo : bHi;
    char* L = &lds[buf][0];
#pragma unroll
    for (int i = 0; i < 4; ++i) {
      gload16(pa + (abase + (unsigned)i * 32768u + kb), L + i * 8192 + t * 16);
      gload16(pb + (boff[i] + kb), L + 32768 + i * 8192 + t * 16);
    }
  };

  f32x4 acc[8][4] = {};

  // Prologue: fill both buffers.
  STAGE(0, 0);
  STAGE(1, 1);

#pragma unroll 1
  for (int kt = 0; kt < 12; ++kt) {
    if (kt == 11) asm volatile("s_waitcnt vmcnt(0)" ::: "memory");
    else          asm volatile("s_waitcnt vmcnt(8)" ::: "memory");
    __builtin_amdgcn_s_barrier();

    const char* L = &lds[kt & 1][0];
    bf16x8 aLoQ[4][2], aHiQ[4][2], bLoQ[2][2], bHiQ[2][2];

    // q0: A rows 0-63 of wave-half + B cols 0-31 of wave-quarter
#pragma unroll
    for (int mi = 0; mi < 4; ++mi)
#pragma unroll
      for (int ks = 0; ks < 2; ++ks) {
        int row = wrow * 128 + mi * 16 + lx;
        aLoQ[mi][ks] = *(const bf16x8*)(L + row * 128 + ((((ks << 2) | (lane >> 4)) ^ (lx & 7)) << 4));
      }
#pragma unroll
    for (int ni = 0; ni < 2; ++ni)
#pragma unroll
      for (int ks = 0; ks < 2; ++ks) {
        int row = wcol * 64 + ni * 16 + lx;
        bLoQ[ni][ks] = *(const bf16x8*)(L + 32768 + row * 128 + ((((ks << 2) | (lane >> 4)) ^ (lx & 7)) << 4));
      }
    __builtin_amdgcn_s_setprio(1);
#pragma unroll
    for (int mi = 0; mi < 4; ++mi)
#pragma unroll
      for (int ni = 0; ni < 2; ++ni)
#pragma unroll
        for (int ks = 0; ks < 2; ++ks)
          acc[mi][ni] = __builtin_amdgcn_mfma_f32_16x16x32_bf16(aLoQ[mi][ks], bLoQ[ni][ks], acc[mi][ni], 0, 0, 0);
    __builtin_amdgcn_s_setprio(0);

    // q1: + B cols 32-63
#pragma unroll
    for (int ni = 0; ni < 2; ++ni)
#pragma unroll
      for (int ks = 0; ks < 2; ++ks) {
        int row = wcol * 64 + (ni + 2) * 16 + lx;
        bHiQ[ni][ks] = *(const bf16x8*)(L + 32768 + row * 128 + ((((ks << 2) | (lane >> 4)) ^ (lx & 7)) << 4));
      }
    __builtin_amdgcn_s_setprio(1);
#pragma unroll
    for (int mi = 0; mi < 4; ++mi)
#pragma unroll
      for (int ni = 0; ni < 2; ++ni)
#pragma unroll
        for (int ks = 0; ks < 2; ++ks)
          acc[mi][ni + 2] = __builtin_amdgcn_mfma_f32_16x16x32_bf16(aLoQ[mi][ks], bHiQ[ni][ks], acc[mi][ni + 2], 0, 0, 0);
    __builtin_amdgcn_s_setprio(0);

    // q2: A rows 64-127 of wave-half
#pragma unroll
    for (int mi = 0; mi < 4; ++mi)
#pragma unroll
      for (int ks = 0; ks < 2; ++ks) {
        int row = wrow * 128 + (mi + 4) * 16 + lx;
        aHiQ[mi][ks] = *(const bf16x8*)(L + row * 128 + ((((ks << 2) | (lane >> 4)) ^ (lx & 7)) << 4));
      }
    __builtin_amdgcn_s_setprio(1);
#pragma unroll
    for (int mi = 0; mi < 4; ++mi)
#pragma unroll
      for (int ni = 0; ni < 2; ++ni)
#pragma unroll
        for (int ks = 0; ks < 2; ++ks)
          acc[mi + 4][ni] = __builtin_amdgcn_mfma_f32_16x16x32_bf16(aHiQ[mi][ks], bLoQ[ni][ks], acc[mi + 4][ni], 0, 0, 0);
    __builtin_amdgcn_s_setprio(0);

    // q3
    __builtin_amdgcn_s_setprio(1);
#pragma unroll
    for (int mi = 0; mi < 4; ++mi)
#pragma unroll
      for (int ni = 0; ni < 2; ++ni)
#pragma unroll
        for (int ks = 0; ks < 2; ++ks)
          acc[mi + 4][ni + 2] = __builtin_amdgcn_mfma_f32_16x16x32_bf16(aHiQ[mi][ks], bHiQ[ni][ks], acc[mi + 4][ni + 2], 0, 0, 0);
    __builtin_amdgcn_s_setprio(0);

    asm volatile("" ::: "memory");
    __builtin_amdgcn_s_barrier();
    if (kt < 10) STAGE(kt + 2, kt & 1);
  }

  // Epilogue: contiguous-row stores. C/D layout col = lane&15, row = (lane>>4)*4+jj.
  size_t obase = (size_t)B_SZ + (size_t)(r * 2 + side) * CN;
  int gcb = ntile * 256 + wcol * 64 + lx;
  int grb = ctile * 256 + wrow * 128 + ((lane >> 4) << 2);
#pragma unroll
  for (int mi = 0; mi < 8; ++mi) {
#pragma unroll
    for (int ni = 0; ni < 4; ++ni) {
      int gc = gcb + ni * 16;
#pragma unroll
      for (int jj = 0; jj < 4; ++jj) {
        int gr = grb + mi * 16 + jj;
        size_t idx = obase + (size_t)gr * N_SZ + gc;
        float v = acc[mi][ni][jj];
        __builtin_nontemporal_store(v, &out[idx]);
        __builtin_nontemporal_store(sigmoidf_(v), &out[(size_t)L_SZ + idx]);
      }
    }
  }
}

// ---------------------------------------------------------------------------
extern "C" void kernel_launch(void* const* d_in, const int* in_sizes, int n_in,
                              void* d_out, int out_size, void* d_ws, size_t ws_size,
                              hipStream_t stream) {
  const float* emb   = (const float*)d_in[0];
  const float* trans = (const float*)d_in[1];
  const int*   rels  = (const int*)d_in[2];
  const int*   order = (const int*)d_in[3];
  const int*   negL  = (const int*)d_in[4];
  const int*   negR  = (const int*)d_in[5];
  float* out = (float*)d_out;

  unsigned short* sortArr = (unsigned short*)d_ws;
  int* inv = (int*)((char*)d_ws + (size_t)16 * 1024 * 1024);

  inv_kernel<<<32, 256, 0, stream>>>(order, inv);
  prep_kernel<<<B_SZ / 4, 256, 0, stream>>>(emb, trans, rels, inv, out, sortArr);
  negs_kernel<<<256, 512, 0, stream>>>(sortArr, inv, negL, negR, out);
}

// Round 9
// 57.458 us; speedup vs baseline: 4.3942x; 1.3299x over previous
//
#include <hip/hip_runtime.h>
#include <hip/hip_bf16.h>
#include <stdint.h>

// Problem constants (fixed by the reference)
#define B_SZ 8192
#define D_SZ 256
#define R_SZ 8
#define N_SZ 1024
#define C_SZ (B_SZ / R_SZ)          // 1024
#define CN   (C_SZ * N_SZ)          // 1048576
#define L_SZ (B_SZ + 2 * R_SZ * CN) // 16785408 (logits length)
#define BD   (B_SZ * D_SZ)          // elements per ws array

typedef short bf16x8 __attribute__((ext_vector_type(8)));
typedef float f32x4  __attribute__((ext_vector_type(4)));

static __device__ __forceinline__ unsigned short f2bf(float f) {
  unsigned u = __float_as_uint(f);
  u += 0x7FFFu + ((u >> 16) & 1u);   // RNE
  return (unsigned short)(u >> 16);
}
static __device__ __forceinline__ float bf2f(unsigned short h) {
  return __uint_as_float(((unsigned)h) << 16);
}
static __device__ __forceinline__ float sigmoidf_(float x) {
  return 1.0f / (1.0f + __expf(-x));
}
static __device__ __forceinline__ void gload16(const void* g, void* l) {
  __builtin_amdgcn_global_load_lds(
      (const __attribute__((address_space(1))) void*)g,
      (__attribute__((address_space(3))) void*)l, 16, 0, 0);
}

// ---------------------------------------------------------------------------
// Phase 1: F-reduce emb -> lhs/rhs, split into bf16 hi+lo in ws, pos logits.
// One wave per batch row i. 2048 blocks x 256 threads.  (R1 verbatim)
// ---------------------------------------------------------------------------
__global__ __launch_bounds__(256) void prep_kernel(
    const float* __restrict__ emb, const float* __restrict__ trans,
    const int* __restrict__ rels, float* __restrict__ out,
    unsigned short* __restrict__ ws) {
  unsigned short* lhs_hi = ws;
  unsigned short* lhs_lo = ws + (size_t)BD;
  unsigned short* rhs_hi = ws + (size_t)2 * BD;
  unsigned short* rhs_lo = ws + (size_t)3 * BD;

  int wave = threadIdx.x >> 6;
  int lane = threadIdx.x & 63;
  int i = blockIdx.x * 4 + wave;            // 0..B-1

  const float4* emb4 = (const float4*)emb;  // emb row j = 128 float4 (F*D=512 f32)
  size_t bl = (size_t)(2 * i) * 128;
  size_t br = (size_t)(2 * i + 1) * 128;
  float4 a0 = emb4[bl + lane];
  float4 a1 = emb4[bl + 64 + lane];
  float4 b0 = emb4[br + lane];
  float4 b1 = emb4[br + 64 + lane];
  float lh[4] = {a0.x + a1.x, a0.y + a1.y, a0.z + a1.z, a0.w + a1.w};
  float rh[4] = {b0.x + b1.x, b0.y + b1.y, b0.z + b1.z, b0.w + b1.w};

  int rel = rels[i];
  float4 t = ((const float4*)trans)[rel * 64 + lane];
  float tt[4] = {t.x, t.y, t.z, t.w};

  float p = 0.f;
#pragma unroll
  for (int j = 0; j < 4; ++j) p += lh[j] * (rh[j] + tt[j]);
#pragma unroll
  for (int off = 32; off; off >>= 1) p += __shfl_xor(p, off, 64);
  if (lane == 0) {
    out[i] = p;
    out[(size_t)L_SZ + i] = sigmoidf_(p);
  }

  unsigned short h[4], l[4];
#pragma unroll
  for (int j = 0; j < 4; ++j) {
    h[j] = f2bf(lh[j]);
    l[j] = f2bf(lh[j] - bf2f(h[j]));
  }
  *(ushort4*)(lhs_hi + (size_t)i * 256 + lane * 4) = make_ushort4(h[0], h[1], h[2], h[3]);
  *(ushort4*)(lhs_lo + (size_t)i * 256 + lane * 4) = make_ushort4(l[0], l[1], l[2], l[3]);
#pragma unroll
  for (int j = 0; j < 4; ++j) {
    h[j] = f2bf(rh[j]);
    l[j] = f2bf(rh[j] - bf2f(h[j]));
  }
  *(ushort4*)(rhs_hi + (size_t)i * 256 + lane * 4) = make_ushort4(h[0], h[1], h[2], h[3]);
  *(ushort4*)(rhs_lo + (size_t)i * 256 + lane * 4) = make_ushort4(l[0], l[1], l[2], l[3]);
}

// ---------------------------------------------------------------------------
// Phase 2: R1's gather-GEMM verbatim (128x128 tile, 4 waves 2x2, BK=64,
// single-buffer 64KB staging, 2-barrier compiler-managed schedule, 1024
// blocks = 2/CU). ONLY change vs R1: the epilogue goes through an LDS
// transpose (float[128][132], unioned with the dead stage buffers) and
// streams out with PLAIN f32x4 stores where each instruction writes two
// dense 512B row-segments (fill-kernel pattern) — write-path experiment.
// ---------------------------------------------------------------------------
__global__ __launch_bounds__(256, 2) void negs_kernel(
    const unsigned short* __restrict__ ws,
    const int* __restrict__ order,
    const int* __restrict__ negL, const int* __restrict__ negR,
    float* __restrict__ out) {
  __shared__ char smem[67584];  // 64KB stage (4x16KB) | 66KB float[128][132]

  const unsigned short* lhs_hi = ws;
  const unsigned short* lhs_lo = ws + (size_t)BD;
  const unsigned short* rhs_hi = ws + (size_t)2 * BD;
  const unsigned short* rhs_lo = ws + (size_t)3 * BD;

  int bid = blockIdx.x;
  int ntile = bid & 7;
  int ctile = (bid >> 3) & 7;
  int side  = (bid >> 6) & 1;
  int r     = bid >> 7;

  int wave = threadIdx.x >> 6;
  int lane = threadIdx.x & 63;
  int wrow = wave >> 1, wcol = wave & 1;

  // wave w stages array w: 0=A_hi 1=A_lo 2=B_hi 3=B_lo
  const unsigned short* srcp;
  const int* idxp;
  int idxbase;
  if (wave < 2) {
    idxp = order;
    idxbase = r * C_SZ + ctile * 128;
    srcp = (wave == 0) ? (side ? lhs_hi : rhs_hi) : (side ? lhs_lo : rhs_lo);
  } else {
    idxp = side ? negR : negL;
    idxbase = r * N_SZ + ntile * 128;
    srcp = (wave == 2) ? (side ? rhs_hi : lhs_hi) : (side ? rhs_lo : lhs_lo);
  }

  // Preload gather offsets: lane stages chunk (lane&7) of row (it*8 + lane>>3).
  unsigned goff[16];
#pragma unroll
  for (int it = 0; it < 16; ++it) {
    int grow = idxp[idxbase + it * 8 + (lane >> 3)];
    goff[it] = (unsigned)grow * 512u + ((unsigned)(((lane & 7) ^ (lane >> 3))) << 4);
  }
  char* myLds = smem + wave * 16384;

  f32x4 acc[4][4] = {};

  for (int kc = 0; kc < 4; ++kc) {
#pragma unroll
    for (int it = 0; it < 16; ++it) {
      gload16((const char*)srcp + goff[it] + kc * 128, myLds + it * 1024);
    }
    __syncthreads();

#pragma unroll
    for (int ks = 0; ks < 2; ++ks) {
      int kchunk = ks * 4 + (lane >> 4);  // 16B chunk index within 128B row
      bf16x8 ah[4], al_[4], bh[4], bl_[4];
#pragma unroll
      for (int mi = 0; mi < 4; ++mi) {
        int row = wrow * 64 + mi * 16 + (lane & 15);
        int off = row * 128 + ((kchunk ^ (lane & 7)) << 4);
        ah[mi]  = *(const bf16x8*)(smem + off);
        al_[mi] = *(const bf16x8*)(smem + 16384 + off);
      }
#pragma unroll
      for (int ni = 0; ni < 4; ++ni) {
        int row = wcol * 64 + ni * 16 + (lane & 15);
        int off = row * 128 + ((kchunk ^ (lane & 7)) << 4);
        bh[ni]  = *(const bf16x8*)(smem + 32768 + off);
        bl_[ni] = *(const bf16x8*)(smem + 49152 + off);
      }
#pragma unroll
      for (int mi = 0; mi < 4; ++mi)
#pragma unroll
        for (int ni = 0; ni < 4; ++ni) {
          acc[mi][ni] = __builtin_amdgcn_mfma_f32_16x16x32_bf16(ah[mi],  bh[ni],  acc[mi][ni], 0, 0, 0);
          acc[mi][ni] = __builtin_amdgcn_mfma_f32_16x16x32_bf16(al_[mi], bh[ni],  acc[mi][ni], 0, 0, 0);
          acc[mi][ni] = __builtin_amdgcn_mfma_f32_16x16x32_bf16(ah[mi],  bl_[ni], acc[mi][ni], 0, 0, 0);
        }
    }
    __syncthreads();
  }

  // --- Epilogue v2: densify writes via LDS transpose ---------------------
  // acc -> tr[128][132] (pad 132 floats: row-diff bank offset 4 -> <=2-way).
  float* tr = (float*)smem;  // stage buffers dead after final __syncthreads
#pragma unroll
  for (int mi = 0; mi < 4; ++mi)
#pragma unroll
    for (int ni = 0; ni < 4; ++ni)
#pragma unroll
      for (int jj = 0; jj < 4; ++jj) {
        int rl = wrow * 64 + mi * 16 + ((lane >> 4) << 2) + jj;  // c-dim 0..127
        int cl = wcol * 64 + ni * 16 + (lane & 15);              // n-dim 0..127
        tr[rl * 132 + cl] = acc[mi][ni][jj];
      }
  __syncthreads();

  // Stream out: iter k, wave w writes rows w*32+k*2+(lane>>5), lanes 0..31
  // cover 512B of one row (f32x4 each) -> 2 dense 512B segments / instr.
  size_t obase = (size_t)B_SZ + ((size_t)(r * 2 + side)) * CN;
  int gcb = ntile * 128 + (lane & 31) * 4;
#pragma unroll
  for (int k = 0; k < 16; ++k) {
    int rl = wave * 32 + k * 2 + (lane >> 5);
    f32x4 v = *(const f32x4*)(tr + rl * 132 + (lane & 31) * 4);
    size_t idx = obase + (size_t)(ctile * 128 + rl) * N_SZ + gcb;
    *(f32x4*)(out + idx) = v;
    f32x4 s;
#pragma unroll
    for (int u = 0; u < 4; ++u) s[u] = sigmoidf_(v[u]);
    *(f32x4*)(out + (size_t)L_SZ + idx) = s;
  }
}

// ---------------------------------------------------------------------------
extern "C" void kernel_launch(void* const* d_in, const int* in_sizes, int n_in,
                              void* d_out, int out_size, void* d_ws, size_t ws_size,
                              hipStream_t stream) {
  const float* emb   = (const float*)d_in[0];
  const float* trans = (const float*)d_in[1];
  const int*   rels  = (const int*)d_in[2];
  const int*   order = (const int*)d_in[3];
  const int*   negL  = (const int*)d_in[4];
  const int*   negR  = (const int*)d_in[5];
  float* out = (float*)d_out;
  unsigned short* ws = (unsigned short*)d_ws;  // 4 * B*D * 2B = 16 MB

  prep_kernel<<<B_SZ / 4, 256, 0, stream>>>(emb, trans, rels, out, ws);
  negs_kernel<<<R_SZ * 2 * 8 * 8, 256, 0, stream>>>(ws, order, negL, negR, out);
}